// Round 3
// baseline (3699.115 us; speedup 1.0000x reference)
//
#include <hip/hip_runtime.h>
#include <hip/hip_bf16.h>

// RPN proposal head for MI355X.
// conv3x3: f64 acc, f64 LDS tiles (cvt once at stage), pad-1/4 A-layout,
// 8oc x 4col register blocking -> 97% of VALU-busy is v_fma_f64.
// Then: 1x1 heads + sigmoid + decode (f64) -> hist -> bucket threshold ->
// compact -> bitonic top-6000 -> NMS mask -> serial-scan NMS -> top-300.
//
// f64 on the score path: output row assignment is decided by score
// comparisons with gaps ~1e-5; fp32 drift risks row swaps >> 40.96 absmax
// threshold. fp32*fp32 is exact in double FMA. Summation order (bias, then
// ic asc, ky asc, kx asc) is kept bit-identical across kernel versions.

#define HH 128
#define WW 128
#define HW 16384
#define CC 512
#define NANCH 9
#define NTOT 147456          // HW * 9
#define PRE_TOPN 6000
#define POST_TOPN 300
#define NMS_WORDS 94         // ceil(6000/64)
#define CAND_CAP 16384

typedef unsigned int u32;
typedef unsigned long long u64;

// Base anchors from _base_anchors(16): scales {8,16,32} x ratios {.5,1,2},
// numpy banker's rounding applied.
__constant__ float c_anch[9][4] = {
  { -84.f,  -40.f,  99.f,  55.f},
  {-176.f,  -88.f, 191.f, 103.f},
  {-360.f, -184.f, 375.f, 199.f},
  { -56.f,  -56.f,  71.f,  71.f},
  {-120.f, -120.f, 135.f, 135.f},
  {-248.f, -248.f, 263.f, 263.f},
  { -36.f,  -80.f,  51.f,  95.f},
  { -80.f, -168.f,  95.f, 183.f},
  {-168.f, -344.f, 183.f, 351.f}
};

// ---------------------------------------------------------------- conv 3x3
// block: 64 oc x (1 row x 128 cols); 256 threads = 8 ocg x 32 col-lanes.
// Thread: 8 oc x 4 contiguous cols -> acc[8][4] f64 (64 VGPRs).
// LDS tiles stored as f64 (converted once when staged): no per-read cvt.
// A-tile padded 1 double per 4 (idx = c' + c'/4): lane stride 5 doubles =
// 2-way bank aliasing (free). W reads are wave-broadcast (ocg-uniform addr).
// grid: 1024 = 8 oc-tiles (pinned via bid&7) x 128 rows.
__global__ __launch_bounds__(256, 3)
void conv3x3(const float* __restrict__ feat, const float* __restrict__ wconv,
             const float* __restrict__ bias, float* __restrict__ out)
{
  // c' = input col + 1 (c' in [0,129]); idx(c') = c' + (c'>>2) in [0,161].
  __shared__ double sA[4][3][162];   // 15.6 KB
  __shared__ double sW[36][64];      // 18.4 KB  [(ic*9+ky*3+kx)][oc]
  const int tid = threadIdx.x;
  const int oc0 = (blockIdx.x & 7) << 6;   // oc tile -> fixed XCD
  const int r   = blockIdx.x >> 3;         // output row 0..127
  const int ocg = tid >> 5;                // 0..7, 8 oc each
  const int p   = tid & 31;                // column lane: cols 4p..4p+3

  // zero halo slots idx 0 (c'=0) and idx 161 (c'=129); staging writes 1..160
  if (tid < 24) {
    int ic = tid / 6, rm = tid % 6;
    sA[ic][rm >> 1][(rm & 1) ? 161 : 0] = 0.0;
  }

  double acc[8][4];
  #pragma unroll
  for (int o = 0; o < 8; ++o) {
    double bv = (double)bias[oc0 + ocg * 8 + o];
    #pragma unroll
    for (int j = 0; j < 4; ++j) acc[o][j] = bv;
  }

  for (int ic0 = 0; ic0 < CC; ic0 += 4) {
    __syncthreads();
    // stage A: 4 ic x 3 rows x 128 cols = 384 float4 loads, cvt, f64 writes
    #pragma unroll
    for (int k = 0; k < 2; ++k) {
      int s = tid + 256 * k;
      if (s < 384) {
        int icr = s >> 5;                 // 0..11
        int ic = icr / 3, rr = icr % 3;
        int lam = s & 31;
        int grow = r - 1 + rr;
        float4 v = make_float4(0.f, 0.f, 0.f, 0.f);
        if (grow >= 0 && grow < HH)
          v = *reinterpret_cast<const float4*>(
                &feat[(ic0 + ic) * HW + grow * WW + lam * 4]);
        double* dst = &sA[ic][rr][5 * lam];   // c' = 4*lam+1.. -> idx 5lam+{1,2,3,5}
        dst[1] = (double)v.x;
        dst[2] = (double)v.y;
        dst[3] = (double)v.z;
        dst[5] = (double)v.w;
      }
    }
    // stage W: 4 ic x 9 taps x 64 oc; thread = (ic=part, oc): 9 floats
    {
      int part = tid >> 6, oc = tid & 63;
      const float* wp = &wconv[(size_t)((oc0 + oc) * CC + ic0 + part) * 9];
      #pragma unroll
      for (int t = 0; t < 9; ++t)
        sW[part * 9 + t][oc] = (double)wp[t];
    }
    __syncthreads();

    #pragma unroll
    for (int ic = 0; ic < 4; ++ic) {
      #pragma unroll
      for (int ky = 0; ky < 3; ++ky) {
        const double* arow = &sA[ic][ky][5 * p];
        double a0 = arow[0];   // c' = 4p   (input col 4p-1)
        double a1 = arow[1];   // c' = 4p+1 (input col 4p)
        double a2 = arow[2];
        double a3 = arow[3];
        double a4 = arow[5];   // c' = 4p+4
        double a5 = arow[6];   // c' = 4p+5 (input col 4p+4)
        #pragma unroll
        for (int kx = 0; kx < 3; ++kx) {
          const double* wrow = &sW[ic * 9 + ky * 3 + kx][ocg * 8];
          double w0 = wrow[0], w1 = wrow[1], w2 = wrow[2], w3 = wrow[3];
          double w4 = wrow[4], w5 = wrow[5], w6 = wrow[6], w7 = wrow[7];
          double b0, b1, b2, b3;
          if (kx == 0)      { b0 = a0; b1 = a1; b2 = a2; b3 = a3; }
          else if (kx == 1) { b0 = a1; b1 = a2; b2 = a3; b3 = a4; }
          else              { b0 = a2; b1 = a3; b2 = a4; b3 = a5; }
          acc[0][0] = fma(b0, w0, acc[0][0]); acc[0][1] = fma(b1, w0, acc[0][1]);
          acc[0][2] = fma(b2, w0, acc[0][2]); acc[0][3] = fma(b3, w0, acc[0][3]);
          acc[1][0] = fma(b0, w1, acc[1][0]); acc[1][1] = fma(b1, w1, acc[1][1]);
          acc[1][2] = fma(b2, w1, acc[1][2]); acc[1][3] = fma(b3, w1, acc[1][3]);
          acc[2][0] = fma(b0, w2, acc[2][0]); acc[2][1] = fma(b1, w2, acc[2][1]);
          acc[2][2] = fma(b2, w2, acc[2][2]); acc[2][3] = fma(b3, w2, acc[2][3]);
          acc[3][0] = fma(b0, w3, acc[3][0]); acc[3][1] = fma(b1, w3, acc[3][1]);
          acc[3][2] = fma(b2, w3, acc[3][2]); acc[3][3] = fma(b3, w3, acc[3][3]);
          acc[4][0] = fma(b0, w4, acc[4][0]); acc[4][1] = fma(b1, w4, acc[4][1]);
          acc[4][2] = fma(b2, w4, acc[4][2]); acc[4][3] = fma(b3, w4, acc[4][3]);
          acc[5][0] = fma(b0, w5, acc[5][0]); acc[5][1] = fma(b1, w5, acc[5][1]);
          acc[5][2] = fma(b2, w5, acc[5][2]); acc[5][3] = fma(b3, w5, acc[5][3]);
          acc[6][0] = fma(b0, w6, acc[6][0]); acc[6][1] = fma(b1, w6, acc[6][1]);
          acc[6][2] = fma(b2, w6, acc[6][2]); acc[6][3] = fma(b3, w6, acc[6][3]);
          acc[7][0] = fma(b0, w7, acc[7][0]); acc[7][1] = fma(b1, w7, acc[7][1]);
          acc[7][2] = fma(b2, w7, acc[7][2]); acc[7][3] = fma(b3, w7, acc[7][3]);
        }
      }
    }
  }

  #pragma unroll
  for (int o = 0; o < 8; ++o) {
    float4 v;
    v.x = (float)acc[o][0]; v.y = (float)acc[o][1];
    v.z = (float)acc[o][2]; v.w = (float)acc[o][3];
    *reinterpret_cast<float4*>(
      &out[(size_t)(oc0 + ocg * 8 + o) * HW + r * WW + 4 * p]) = v;
  }
}

// ------------------------------------------- 1x1 heads + sigmoid + decode
__global__ __launch_bounds__(256, 2)
void conv1x1_decode(const float* __restrict__ rfeat, const float* __restrict__ wsc,
                    const float* __restrict__ bsc, const float* __restrict__ wbb,
                    const float* __restrict__ bbb, const int* __restrict__ im_info,
                    float* __restrict__ scores, double4* __restrict__ props,
                    u32* __restrict__ hist)
{
  __shared__ float  sA[32][64];
  __shared__ float  sW[32][56];
  __shared__ double sOut[64][56];
  const int tid  = threadIdx.x;
  const int px0  = blockIdx.x * 64;
  const int q    = tid >> 6;        // 0..3 -> 14 outputs each
  const int px_l = tid & 63;
  const int o0   = q * 14;

  double acc[14];
  #pragma unroll
  for (int o = 0; o < 14; ++o) {
    int oo = o0 + o;
    float b = 0.f;
    if (oo < 18) b = bsc[oo];
    else if (oo < 54) b = bbb[oo - 18];
    acc[o] = (double)b;
  }

  for (int ic0 = 0; ic0 < CC; ic0 += 32) {
    __syncthreads();
    #pragma unroll
    for (int k = 0; k < 2; ++k) {
      int s  = tid + 256 * k;
      int ic = s >> 4;
      int c4 = (s & 15) << 2;
      *reinterpret_cast<float4*>(&sA[ic][c4]) =
        *reinterpret_cast<const float4*>(&rfeat[(ic0 + ic) * HW + px0 + c4]);
    }
    for (int idx = tid; idx < 32 * 56; idx += 256) {
      int ic = idx / 56, o = idx % 56;
      float v = 0.f;
      if (o < 18) v = wsc[o * CC + ic0 + ic];
      else if (o < 54) v = wbb[(o - 18) * CC + ic0 + ic];
      sW[ic][o] = v;
    }
    __syncthreads();
    for (int ic = 0; ic < 32; ++ic) {
      double a = (double)sA[ic][px_l];
      #pragma unroll
      for (int o = 0; o < 14; ++o)
        acc[o] = fma(a, (double)sW[ic][o0 + o], acc[o]);
    }
  }
  #pragma unroll
  for (int o = 0; o < 14; ++o) sOut[px_l][o0 + o] = acc[o];
  __syncthreads();

  const double im_h = (double)im_info[0];
  const double im_w = (double)im_info[1];
  const double BCLIP = 4.1351665567423557;   // log(1000/16)
  for (int t = tid; t < 64 * NANCH; t += 256) {
    int pl = t / 9, a = t % 9;
    int gp = px0 + pl;
    double l0 = sOut[pl][a], l1 = sOut[pl][9 + a];
    double sc = 1.0 / (1.0 + exp(l0 - l1));
    float scf = (float)sc;
    int gi = gp * 9 + a;
    scores[gi] = scf;
    atomicAdd(&hist[__float_as_uint(scf) >> 16], 1u);

    double dx = sOut[pl][18 + 4 * a + 0];
    double dy = sOut[pl][18 + 4 * a + 1];
    double dw = sOut[pl][18 + 4 * a + 2];
    double dh = sOut[pl][18 + 4 * a + 3];
    int wq = gp & 127, hq = gp >> 7;
    double ax1 = (double)c_anch[a][0] + 16.0 * wq;
    double ay1 = (double)c_anch[a][1] + 16.0 * hq;
    double ax2 = (double)c_anch[a][2] + 16.0 * wq;
    double ay2 = (double)c_anch[a][3] + 16.0 * hq;
    double aw = ax2 - ax1 + 1.0, ah = ay2 - ay1 + 1.0;
    double acx = ax1 + 0.5 * aw,  acy = ay1 + 0.5 * ah;
    dw = fmin(fmax(dw, -BCLIP), BCLIP);
    dh = fmin(fmax(dh, -BCLIP), BCLIP);
    double pcx = dx * aw + acx, pcy = dy * ah + acy;
    double pw = exp(dw) * aw,   ph = exp(dh) * ah;
    double x1 = fmin(fmax(pcx - 0.5 * pw, 0.0), im_w - 1.0);
    double y1 = fmin(fmax(pcy - 0.5 * ph, 0.0), im_h - 1.0);
    double x2 = fmin(fmax(pcx + 0.5 * pw, 0.0), im_w - 1.0);
    double y2 = fmin(fmax(pcy + 0.5 * ph, 0.0), im_h - 1.0);
    props[gi] = make_double4(x1, y1, x2, y2);
  }
}

// -------------------------------------------- histogram suffix scan -> cutoff
__global__ __launch_bounds__(1024)
void scan_hist(const u32* __restrict__ hist, u32* __restrict__ scal)
{
  __shared__ u32 suf[1024];
  const int t = threadIdx.x;
  u32 s = 0;
  for (int k = 0; k < 64; ++k) s += hist[t * 64 + k];
  suf[t] = s;
  __syncthreads();
  for (int off = 1; off < 1024; off <<= 1) {
    u32 v = (t + off < 1024) ? suf[t + off] : 0u;
    __syncthreads();
    suf[t] += v;
    __syncthreads();
  }
  u32 here = suf[t];
  u32 next = (t < 1023) ? suf[t + 1] : 0u;
  if (here >= PRE_TOPN && (t == 1023 || next < PRE_TOPN)) {
    u32 cum = next;
    int T = t * 64;
    for (int b = 63; b >= 0; --b) {
      cum += hist[t * 64 + b];
      if (cum >= PRE_TOPN) { T = t * 64 + b; break; }
    }
    scal[1] = (u32)T;
  }
}

// ------------------------------------------------------------------ compact
__global__ void compact_cand(const float* __restrict__ scores,
                             u32* __restrict__ scal, u64* __restrict__ cand)
{
  int t = blockIdx.x * 256 + threadIdx.x;
  if (t >= NTOT) return;
  u32 bits = __float_as_uint(scores[t]);
  if ((bits >> 16) >= scal[1]) {
    u32 pos = atomicAdd(&scal[0], 1u);
    if (pos < CAND_CAP)
      cand[pos] = ((u64)bits << 32) | (u64)(0xFFFFFFFFu - (u32)t);
  }
}

// -------------------------- single-block bitonic sort (desc) + top-6000 gather
// key = score_bits<<32 | ~index => desc sort == (score desc, index asc) ==
// jax.lax.top_k tie semantics. Sort size 8192 when candidates fit (usual).
__global__ __launch_bounds__(1024)
void sort_topk(const u64* __restrict__ cand, const u32* __restrict__ scal,
               const double4* __restrict__ props, float* __restrict__ tscore,
               double4* __restrict__ boxes)
{
  __shared__ u64 sk[CAND_CAP];      // 128 KiB LDS
  u32 n = scal[0]; if (n > CAND_CAP) n = CAND_CAP;
  const int SZ = (n <= 8192) ? 8192 : CAND_CAP;
  for (int t = threadIdx.x; t < SZ; t += 1024)
    sk[t] = (t < (int)n) ? cand[t] : 0ull;
  __syncthreads();
  for (int k = 2; k <= SZ; k <<= 1)
    for (int j = k >> 1; j > 0; j >>= 1) {
      for (int t = threadIdx.x; t < SZ; t += 1024) {
        int p = t ^ j;
        if (p > t) {
          u64 va = sk[t], vb = sk[p];
          bool sw = ((t & k) == 0) ? (va < vb) : (va > vb);
          if (sw) { sk[t] = vb; sk[p] = va; }
        }
      }
      __syncthreads();
    }
  for (int t = threadIdx.x; t < PRE_TOPN; t += 1024) {
    u64 key = sk[t];
    u32 idx = 0xFFFFFFFFu - (u32)key;
    tscore[t] = __uint_as_float((u32)(key >> 32));
    boxes[t]  = props[idx];
  }
}

// ------------------------------------------------------------- NMS bit mask
__global__ __launch_bounds__(64)
void nms_mask(const double4* __restrict__ boxes, u64* __restrict__ mask)
{
  const int bi = blockIdx.y, bj = blockIdx.x;
  const int t = threadIdx.x;
  const int i = bi * 64 + t;
  if (bj < bi) { if (i < PRE_TOPN) mask[(u32)i * NMS_WORDS + bj] = 0ull; return; }
  __shared__ double4 cb[64];
  __shared__ double  ca[64];
  const int j0 = bj * 64;
  if (j0 + t < PRE_TOPN) {
    double4 b = boxes[j0 + t];
    cb[t] = b;
    ca[t] = (b.z - b.x + 1.0) * (b.w - b.y + 1.0);
  }
  __syncthreads();
  if (i >= PRE_TOPN) return;
  double4 bb = boxes[i];
  double ai = (bb.z - bb.x + 1.0) * (bb.w - bb.y + 1.0);
  const int jmax = min(64, PRE_TOPN - j0);
  u64 word = 0ull;
  for (int jj = 0; jj < jmax; ++jj) {
    int j = j0 + jj;
    if (j <= i) continue;
    double4 cj = cb[jj];
    double iw = fmin(bb.z, cj.z) - fmax(bb.x, cj.x) + 1.0;
    double ih = fmin(bb.w, cj.w) - fmax(bb.y, cj.y) + 1.0;
    iw = fmax(iw, 0.0); ih = fmax(ih, 0.0);
    double inter = iw * ih;
    double iou = inter / (ai + ca[jj] - inter);
    if (iou > 0.7) word |= (1ull << jj);
  }
  mask[(u32)i * NMS_WORDS + bj] = word;
}

// -------------------- serial NMS scan + top-300 select + output write (1 block)
__global__ __launch_bounds__(256)
void nms_finalize(const u64* __restrict__ mask, const double4* __restrict__ boxes,
                  const float* __restrict__ tscore, float* __restrict__ out)
{
  __shared__ u64 rem[NMS_WORDS];
  __shared__ u64 alv[NMS_WORDS];
  __shared__ int rows[68];
  __shared__ int nrows;
  __shared__ int pre[NMS_WORDS + 1];
  __shared__ int keep[POST_TOPN];
  const int tid = threadIdx.x;
  if (tid < NMS_WORDS) rem[tid] = 0ull;
  __syncthreads();

  for (int c = 0; c < NMS_WORDS; ++c) {
    if (tid < 64) {
      int row = c * 64 + tid;
      u64 m = (row < PRE_TOPN) ? mask[(u32)row * NMS_WORDS + c] : 0ull;
      u64 cur = rem[c];
      for (int b = 0; b < 64; ++b) {
        u64 mb = (u64)__shfl((long long)m, b, 64);
        if (!((cur >> b) & 1ull)) cur |= mb;
      }
      if (tid == 0) {
        rem[c] = cur;
        u64 valid = (c == NMS_WORDS - 1) ? ((1ull << 48) - 1ull) : ~0ull;
        alv[c] = (~cur) & valid;
      }
    }
    if (tid == 255) nrows = 0;
    __syncthreads();
    if (tid < 64 && ((alv[c] >> tid) & 1ull))
      rows[atomicAdd(&nrows, 1)] = c * 64 + tid;
    __syncthreads();
    const int nr = nrows;
    if (tid < 4 && nr > 0) rows[nr + tid] = rows[0];
    __syncthreads();
    if (nr > 0) {
      int w = c + 1 + (tid >> 1);
      if (w < NMS_WORDS) {
        const int sl = tid & 1;
        const int G = (nr + 3) >> 2;
        u64 acc = 0ull;
        for (int g = sl; g < G; g += 2) {
          int b = g << 2;
          int r0 = rows[b], r1 = rows[b + 1], r2 = rows[b + 2], r3 = rows[b + 3];
          acc |= mask[(u32)r0 * NMS_WORDS + w] | mask[(u32)r1 * NMS_WORDS + w]
               | mask[(u32)r2 * NMS_WORDS + w] | mask[(u32)r3 * NMS_WORDS + w];
        }
        if (acc) atomicOr((unsigned long long*)&rem[w], (unsigned long long)acc);
      }
    }
    __syncthreads();
  }

  if (tid == 0) {
    int s = 0;
    for (int c = 0; c < NMS_WORDS; ++c) { pre[c] = s; s += __popcll(alv[c]); }
    pre[NMS_WORDS] = s;
  }
  __syncthreads();
  const int total = pre[NMS_WORDS];
  if (tid < NMS_WORDS) {
    int p = pre[tid];
    u64 bits = alv[tid];
    while (bits && p < POST_TOPN) {
      int b = __ffsll(bits) - 1;
      bits &= bits - 1;
      keep[p] = tid * 64 + b;
      ++p;
    }
  }
  __syncthreads();
  if (total < POST_TOPN) {
    if (tid == 0) {
      int p = total;
      for (int c = 0; c < NMS_WORDS && p < POST_TOPN; ++c) {
        u64 valid = (c == NMS_WORDS - 1) ? ((1ull << 48) - 1ull) : ~0ull;
        u64 bits = rem[c] & valid;
        while (bits && p < POST_TOPN) {
          int b = __ffsll(bits) - 1;
          bits &= bits - 1;
          keep[p++] = c * 64 + b;
        }
      }
    }
    __syncthreads();
  }

  for (int t = tid; t < POST_TOPN; t += 256) {
    int r = keep[t];
    double4 b = boxes[r];
    out[t * 5 + 0] = 0.f;
    out[t * 5 + 1] = (float)b.x;
    out[t * 5 + 2] = (float)b.y;
    out[t * 5 + 3] = (float)b.z;
    out[t * 5 + 4] = (float)b.w;
    out[POST_TOPN * 5 + t] = tscore[r];
  }
}

// --------------------------------------------------------------------- launch
extern "C" void kernel_launch(void* const* d_in, const int* in_sizes, int n_in,
                              void* d_out, int out_size, void* d_ws, size_t ws_size,
                              hipStream_t stream)
{
  const float* feature = (const float*)d_in[0];
  const int*   im_info = (const int*)d_in[1];
  const float* w_conv  = (const float*)d_in[2];
  const float* b_conv  = (const float*)d_in[3];
  const float* w_sc    = (const float*)d_in[4];
  const float* b_sc    = (const float*)d_in[5];
  const float* w_bb    = (const float*)d_in[6];
  const float* b_bb    = (const float*)d_in[7];
  float* out = (float*)d_out;

  char* ws = (char*)d_ws;
  float*   rfeat  = (float*)(ws);                 // 33,554,432 B
  float*   scores = (float*)(ws + 33554432);      //    589,824 B
  double4* props  = (double4*)(ws + 34144256);    //  4,718,592 B
  u64*     mask   = (u64*)(ws + 34144256);        // alias: used after props' last read
  u32*     hist   = (u32*)(ws + 38862848);        //    262,144 B
  u32*     scal   = (u32*)(ws + 39124992);        //        256 B
  u64*     cand   = (u64*)(ws + 39125248);        //    131,072 B
  float*   tscore = (float*)(ws + 39256320);      //     24,000 B
  double4* boxes  = (double4*)(ws + 39280384);    //    192,000 B

  hipMemsetAsync(hist, 0, 65536 * sizeof(u32), stream);
  hipMemsetAsync(scal, 0, 256, stream);

  conv3x3<<<1024, 256, 0, stream>>>(feature, w_conv, b_conv, rfeat);
  conv1x1_decode<<<256, 256, 0, stream>>>(rfeat, w_sc, b_sc, w_bb, b_bb, im_info,
                                          scores, props, hist);
  scan_hist<<<1, 1024, 0, stream>>>(hist, scal);
  compact_cand<<<(NTOT + 255) / 256, 256, 0, stream>>>(scores, scal, cand);
  sort_topk<<<1, 1024, 0, stream>>>(cand, scal, props, tscore, boxes);
  nms_mask<<<dim3(NMS_WORDS, NMS_WORDS), 64, 0, stream>>>(boxes, mask);
  nms_finalize<<<1, 256, 0, stream>>>(mask, boxes, tscore, out);

  hipMemcpyAsync(out + POST_TOPN * 6, feature, (size_t)CC * HW * sizeof(float),
                 hipMemcpyDeviceToDevice, stream);
}

// Round 6
// 2815.302 us; speedup vs baseline: 1.3139x; 1.3139x over previous
//
#include <hip/hip_runtime.h>
#include <hip/hip_bf16.h>

// RPN proposal head for MI355X.
// wcvt: weights f32 -> f64, [ocgroup][ic][tap][oc8] layout (SGPR-loadable).
// conv3x3: f64 acc; weights via s_load into SGPRs (v_fma_f64 SGPR operand);
//          A-tile f64 in LDS, pad-1/4 layout; acc[8][2] = 32 VGPR -> no spill.
// Then: 1x1 heads + sigmoid + decode (f64) -> hist -> bucket threshold ->
// compact -> bitonic top-6000 -> NMS mask -> serial-scan NMS -> top-300.
//
// f64 on the score path: output row assignment is decided by score
// comparisons with gaps ~1e-5; fp32 drift risks row swaps >> 40.96 absmax
// threshold. fp32*fp32 is exact in double FMA. Summation order (bias, then
// ic asc, ky asc, kx asc) kept bit-identical across kernel versions.

#define HH 128
#define WW 128
#define HW 16384
#define CC 512
#define NANCH 9
#define NTOT 147456          // HW * 9
#define PRE_TOPN 6000
#define POST_TOPN 300
#define NMS_WORDS 94         // ceil(6000/64)
#define CAND_CAP 16384

typedef unsigned int u32;
typedef unsigned long long u64;

// Base anchors from _base_anchors(16): scales {8,16,32} x ratios {.5,1,2},
// numpy banker's rounding applied.
__constant__ float c_anch[9][4] = {
  { -84.f,  -40.f,  99.f,  55.f},
  {-176.f,  -88.f, 191.f, 103.f},
  {-360.f, -184.f, 375.f, 199.f},
  { -56.f,  -56.f,  71.f,  71.f},
  {-120.f, -120.f, 135.f, 135.f},
  {-248.f, -248.f, 263.f, 263.f},
  { -36.f,  -80.f,  51.f,  95.f},
  { -80.f, -168.f,  95.f, 183.f},
  {-168.f, -344.f, 183.f, 351.f}
};

// ------------------------------------------------ weight convert/transpose
// wd[((g*512 + ic)*9 + t)*8 + o8] = (double)wconv[((g*8+o8)*512 + ic)*9 + t]
// Thread indexed by INPUT element (coalesced reads; 64B-granular scattered
// writes -- 28 MB total, negligible).
__global__ __launch_bounds__(256)
void wcvt(const float* __restrict__ wconv, double* __restrict__ wd)
{
  int idx = blockIdx.x * 256 + threadIdx.x;    // 0 .. 2,359,295
  int t  = idx % 9;
  int ic = (idx / 9) & 511;
  int oc = idx / 4608;
  int g  = oc >> 3, o8 = oc & 7;
  wd[(size_t)g * 36864 + ic * 72 + t * 8 + o8] = (double)wconv[idx];
}

// ---------------------------------------------------------------- conv 3x3
// 512 threads = 8 waves. Wave w (readfirstlane-uniform) owns oc
// [oc0+8w, oc0+8w+8); lane l (0..63) owns output cols {2l, 2l+1}.
// acc[8][2] f64 = 32 VGPRs. Weights: scalar s_load from wd (SGPR operand
// in v_fma_f64) -> no VGPR/VALU cost. A-tile: f64 LDS, idx(c')=c'+(c'>>2)
// pad layout (measured conflict-free in r3). grid: 8 oc-tiles x 128 rows;
// oc-tile = bid&7 pins each tile's 2.36MB weight slice to one XCD's L2.
__global__ __launch_bounds__(512)
void conv3x3(const float* __restrict__ feat, const double* __restrict__ wd,
             const float* __restrict__ bias, float* __restrict__ out)
{
  __shared__ double sA[4][3][162];   // 15.6 KB
  const int tid = threadIdx.x;
  const int oc0 = (blockIdx.x & 7) << 6;
  const int r   = blockIdx.x >> 3;
  const int wv  = __builtin_amdgcn_readfirstlane(tid >> 6);  // wave 0..7
  const int l   = tid & 63;

  // a-read indices for c' = 2l..2l+3
  const int c0 = 2 * l;
  const int x0 = c0 + (c0 >> 2);
  const int x1 = (c0 + 1) + ((c0 + 1) >> 2);
  const int x2 = (c0 + 2) + ((c0 + 2) >> 2);
  const int x3 = (c0 + 3) + ((c0 + 3) >> 2);

  // zero halo slots idx 0 (c'=0) and 161 (c'=129)
  if (tid < 24) {
    int ic = tid / 6, rm = tid % 6;
    sA[ic][rm >> 1][(rm & 1) ? 161 : 0] = 0.0;
  }

  double acc[8][2];
  #pragma unroll
  for (int o = 0; o < 8; ++o) {
    double bv = (double)bias[oc0 + wv * 8 + o];
    acc[o][0] = bv; acc[o][1] = bv;
  }

  const double* wg = wd + (size_t)((oc0 >> 3) + wv) * 36864;  // scalar base

  for (int ic0 = 0; ic0 < CC; ic0 += 4) {
    __syncthreads();
    // stage A: 4 ic x 3 rows x 128 cols = 384 float4 (threads 0..383)
    if (tid < 384) {
      int icr = tid >> 5;               // 0..11
      int ic = icr / 3, rr = icr % 3;
      int lam = tid & 31;
      int grow = r - 1 + rr;
      float4 v = make_float4(0.f, 0.f, 0.f, 0.f);
      if (grow >= 0 && grow < HH)
        v = *reinterpret_cast<const float4*>(
              &feat[(ic0 + ic) * HW + grow * WW + lam * 4]);
      double* dst = &sA[ic][rr][5 * lam];   // idx = 5lam + {1,2,3,5}
      dst[1] = (double)v.x;
      dst[2] = (double)v.y;
      dst[3] = (double)v.z;
      dst[5] = (double)v.w;
    }
    __syncthreads();

    const double* wc = wg + ic0 * 72;       // scalar
    #pragma unroll
    for (int ic = 0; ic < 4; ++ic) {
      #pragma unroll
      for (int ky = 0; ky < 3; ++ky) {
        const double* arow = sA[ic][ky];
        double a0 = arow[x0], a1 = arow[x1], a2 = arow[x2], a3 = arow[x3];
        const double* wp = wc + ic * 72 + ky * 24;   // scalar: s_load
        #pragma unroll
        for (int kx = 0; kx < 3; ++kx) {
          double b0 = (kx == 0) ? a0 : ((kx == 1) ? a1 : a2);
          double b1 = (kx == 0) ? a1 : ((kx == 1) ? a2 : a3);
          #pragma unroll
          for (int o = 0; o < 8; ++o) {
            double w = wp[kx * 8 + o];
            acc[o][0] = fma(b0, w, acc[o][0]);
            acc[o][1] = fma(b1, w, acc[o][1]);
          }
        }
      }
    }
  }

  #pragma unroll
  for (int o = 0; o < 8; ++o) {
    float2 v;
    v.x = (float)acc[o][0];
    v.y = (float)acc[o][1];
    *reinterpret_cast<float2*>(
      &out[(size_t)(oc0 + wv * 8 + o) * HW + r * WW + 2 * l]) = v;
  }
}

// ------------------------------------- fallback conv (r2, known-good 2107us)
__global__ __launch_bounds__(256, 4)
void conv3x3_fb(const float* __restrict__ feat, const float* __restrict__ wconv,
                const float* __restrict__ bias, float* __restrict__ out)
{
  __shared__ float sA[8][3][136];
  __shared__ float sW[72][64];
  const int tid  = threadIdx.x;
  const int oc0  = (blockIdx.x & 7) << 6;
  const int r    = blockIdx.x >> 3;
  const int ocg  = tid >> 4;
  const int p    = tid & 15;

  if (tid < 48) {
    int ic = tid / 6, rm = tid % 6;
    sA[ic][rm >> 1][(rm & 1) ? 132 : 3] = 0.f;
  }

  double acc[4][8];
  #pragma unroll
  for (int o = 0; o < 4; ++o) {
    double bv = (double)bias[oc0 + ocg * 4 + o];
    #pragma unroll
    for (int j = 0; j < 8; ++j) acc[o][j] = bv;
  }

  for (int ic0 = 0; ic0 < CC; ic0 += 8) {
    __syncthreads();
    #pragma unroll
    for (int k = 0; k < 3; ++k) {
      int s   = tid + 256 * k;
      int icr = s >> 5;
      int ic  = icr / 3, rr = icr % 3;
      int c4  = (s & 31) << 2;
      int grow = r - 1 + rr;
      float4 v = make_float4(0.f, 0.f, 0.f, 0.f);
      if (grow >= 0 && grow < HH)
        v = *reinterpret_cast<const float4*>(&feat[(ic0 + ic) * HW + grow * WW + c4]);
      *reinterpret_cast<float4*>(&sA[ic][rr][4 + c4]) = v;
    }
    {
      int oc = tid & 63, part = tid >> 6;
      const float* wp = &wconv[(size_t)((oc0 + oc) * CC + ic0) * 9 + part * 18];
      #pragma unroll
      for (int k = 0; k < 18; ++k) sW[part * 18 + k][oc] = wp[k];
    }
    __syncthreads();

    for (int ic = 0; ic < 8; ++ic) {
      #pragma unroll
      for (int ky = 0; ky < 3; ++ky) {
        double w[3][4];
        #pragma unroll
        for (int kx = 0; kx < 3; ++kx)
          #pragma unroll
          for (int o = 0; o < 4; ++o)
            w[kx][o] = (double)sW[ic * 9 + ky * 3 + kx][ocg * 4 + o];
        const float* arow = &sA[ic][ky][4];
        #pragma unroll
        for (int j = 0; j < 8; ++j) {
          int c = p + 16 * j;
          double a0 = (double)arow[c - 1];
          double a1 = (double)arow[c];
          double a2 = (double)arow[c + 1];
          #pragma unroll
          for (int o = 0; o < 4; ++o) {
            acc[o][j] = fma(a0, w[0][o], acc[o][j]);
            acc[o][j] = fma(a1, w[1][o], acc[o][j]);
            acc[o][j] = fma(a2, w[2][o], acc[o][j]);
          }
        }
      }
    }
  }

  #pragma unroll
  for (int o = 0; o < 4; ++o) {
    float* op = &out[(size_t)(oc0 + ocg * 4 + o) * HW + r * WW];
    #pragma unroll
    for (int j = 0; j < 8; ++j)
      op[p + 16 * j] = (float)acc[o][j];
  }
}

// ------------------------------------------- 1x1 heads + sigmoid + decode
__global__ __launch_bounds__(256, 2)
void conv1x1_decode(const float* __restrict__ rfeat, const float* __restrict__ wsc,
                    const float* __restrict__ bsc, const float* __restrict__ wbb,
                    const float* __restrict__ bbb, const int* __restrict__ im_info,
                    float* __restrict__ scores, double4* __restrict__ props,
                    u32* __restrict__ hist)
{
  __shared__ float  sA[32][64];
  __shared__ float  sW[32][56];
  __shared__ double sOut[64][56];
  const int tid  = threadIdx.x;
  const int px0  = blockIdx.x * 64;
  const int q    = tid >> 6;
  const int px_l = tid & 63;
  const int o0   = q * 14;

  double acc[14];
  #pragma unroll
  for (int o = 0; o < 14; ++o) {
    int oo = o0 + o;
    float b = 0.f;
    if (oo < 18) b = bsc[oo];
    else if (oo < 54) b = bbb[oo - 18];
    acc[o] = (double)b;
  }

  for (int ic0 = 0; ic0 < CC; ic0 += 32) {
    __syncthreads();
    #pragma unroll
    for (int k = 0; k < 2; ++k) {
      int s  = tid + 256 * k;
      int ic = s >> 4;
      int c4 = (s & 15) << 2;
      *reinterpret_cast<float4*>(&sA[ic][c4]) =
        *reinterpret_cast<const float4*>(&rfeat[(ic0 + ic) * HW + px0 + c4]);
    }
    for (int idx = tid; idx < 32 * 56; idx += 256) {
      int ic = idx / 56, o = idx % 56;
      float v = 0.f;
      if (o < 18) v = wsc[o * CC + ic0 + ic];
      else if (o < 54) v = wbb[(o - 18) * CC + ic0 + ic];
      sW[ic][o] = v;
    }
    __syncthreads();
    for (int ic = 0; ic < 32; ++ic) {
      double a = (double)sA[ic][px_l];
      #pragma unroll
      for (int o = 0; o < 14; ++o)
        acc[o] = fma(a, (double)sW[ic][o0 + o], acc[o]);
    }
  }
  #pragma unroll
  for (int o = 0; o < 14; ++o) sOut[px_l][o0 + o] = acc[o];
  __syncthreads();

  const double im_h = (double)im_info[0];
  const double im_w = (double)im_info[1];
  const double BCLIP = 4.1351665567423557;   // log(1000/16)
  for (int t = tid; t < 64 * NANCH; t += 256) {
    int pl = t / 9, a = t % 9;
    int gp = px0 + pl;
    double l0 = sOut[pl][a], l1 = sOut[pl][9 + a];
    double sc = 1.0 / (1.0 + exp(l0 - l1));
    float scf = (float)sc;
    int gi = gp * 9 + a;
    scores[gi] = scf;
    atomicAdd(&hist[__float_as_uint(scf) >> 16], 1u);

    double dx = sOut[pl][18 + 4 * a + 0];
    double dy = sOut[pl][18 + 4 * a + 1];
    double dw = sOut[pl][18 + 4 * a + 2];
    double dh = sOut[pl][18 + 4 * a + 3];
    int wq = gp & 127, hq = gp >> 7;
    double ax1 = (double)c_anch[a][0] + 16.0 * wq;
    double ay1 = (double)c_anch[a][1] + 16.0 * hq;
    double ax2 = (double)c_anch[a][2] + 16.0 * wq;
    double ay2 = (double)c_anch[a][3] + 16.0 * hq;
    double aw = ax2 - ax1 + 1.0, ah = ay2 - ay1 + 1.0;
    double acx = ax1 + 0.5 * aw,  acy = ay1 + 0.5 * ah;
    dw = fmin(fmax(dw, -BCLIP), BCLIP);
    dh = fmin(fmax(dh, -BCLIP), BCLIP);
    double pcx = dx * aw + acx, pcy = dy * ah + acy;
    double pw = exp(dw) * aw,   ph = exp(dh) * ah;
    double x1 = fmin(fmax(pcx - 0.5 * pw, 0.0), im_w - 1.0);
    double y1 = fmin(fmax(pcy - 0.5 * ph, 0.0), im_h - 1.0);
    double x2 = fmin(fmax(pcx + 0.5 * pw, 0.0), im_w - 1.0);
    double y2 = fmin(fmax(pcy + 0.5 * ph, 0.0), im_h - 1.0);
    props[gi] = make_double4(x1, y1, x2, y2);
  }
}

// -------------------------------------------- histogram suffix scan -> cutoff
__global__ __launch_bounds__(1024)
void scan_hist(const u32* __restrict__ hist, u32* __restrict__ scal)
{
  __shared__ u32 suf[1024];
  const int t = threadIdx.x;
  u32 s = 0;
  for (int k = 0; k < 64; ++k) s += hist[t * 64 + k];
  suf[t] = s;
  __syncthreads();
  for (int off = 1; off < 1024; off <<= 1) {
    u32 v = (t + off < 1024) ? suf[t + off] : 0u;
    __syncthreads();
    suf[t] += v;
    __syncthreads();
  }
  u32 here = suf[t];
  u32 next = (t < 1023) ? suf[t + 1] : 0u;
  if (here >= PRE_TOPN && (t == 1023 || next < PRE_TOPN)) {
    u32 cum = next;
    int T = t * 64;
    for (int b = 63; b >= 0; --b) {
      cum += hist[t * 64 + b];
      if (cum >= PRE_TOPN) { T = t * 64 + b; break; }
    }
    scal[1] = (u32)T;
  }
}

// ------------------------------------------------------------------ compact
__global__ void compact_cand(const float* __restrict__ scores,
                             u32* __restrict__ scal, u64* __restrict__ cand)
{
  int t = blockIdx.x * 256 + threadIdx.x;
  if (t >= NTOT) return;
  u32 bits = __float_as_uint(scores[t]);
  if ((bits >> 16) >= scal[1]) {
    u32 pos = atomicAdd(&scal[0], 1u);
    if (pos < CAND_CAP)
      cand[pos] = ((u64)bits << 32) | (u64)(0xFFFFFFFFu - (u32)t);
  }
}

// -------------------------- single-block bitonic sort (desc) + top-6000 gather
__global__ __launch_bounds__(1024)
void sort_topk(const u64* __restrict__ cand, const u32* __restrict__ scal,
               const double4* __restrict__ props, float* __restrict__ tscore,
               double4* __restrict__ boxes)
{
  __shared__ u64 sk[CAND_CAP];      // 128 KiB LDS
  u32 n = scal[0]; if (n > CAND_CAP) n = CAND_CAP;
  const int SZ = (n <= 8192) ? 8192 : CAND_CAP;
  for (int t = threadIdx.x; t < SZ; t += 1024)
    sk[t] = (t < (int)n) ? cand[t] : 0ull;
  __syncthreads();
  for (int k = 2; k <= SZ; k <<= 1)
    for (int j = k >> 1; j > 0; j >>= 1) {
      for (int t = threadIdx.x; t < SZ; t += 1024) {
        int p = t ^ j;
        if (p > t) {
          u64 va = sk[t], vb = sk[p];
          bool sw = ((t & k) == 0) ? (va < vb) : (va > vb);
          if (sw) { sk[t] = vb; sk[p] = va; }
        }
      }
      __syncthreads();
    }
  for (int t = threadIdx.x; t < PRE_TOPN; t += 1024) {
    u64 key = sk[t];
    u32 idx = 0xFFFFFFFFu - (u32)key;
    tscore[t] = __uint_as_float((u32)(key >> 32));
    boxes[t]  = props[idx];
  }
}

// ------------------------------------------------------------- NMS bit mask
__global__ __launch_bounds__(64)
void nms_mask(const double4* __restrict__ boxes, u64* __restrict__ mask)
{
  const int bi = blockIdx.y, bj = blockIdx.x;
  const int t = threadIdx.x;
  const int i = bi * 64 + t;
  if (bj < bi) { if (i < PRE_TOPN) mask[(u32)i * NMS_WORDS + bj] = 0ull; return; }
  __shared__ double4 cb[64];
  __shared__ double  ca[64];
  const int j0 = bj * 64;
  if (j0 + t < PRE_TOPN) {
    double4 b = boxes[j0 + t];
    cb[t] = b;
    ca[t] = (b.z - b.x + 1.0) * (b.w - b.y + 1.0);
  }
  __syncthreads();
  if (i >= PRE_TOPN) return;
  double4 bb = boxes[i];
  double ai = (bb.z - bb.x + 1.0) * (bb.w - bb.y + 1.0);
  const int jmax = min(64, PRE_TOPN - j0);
  u64 word = 0ull;
  for (int jj = 0; jj < jmax; ++jj) {
    int j = j0 + jj;
    if (j <= i) continue;
    double4 cj = cb[jj];
    double iw = fmin(bb.z, cj.z) - fmax(bb.x, cj.x) + 1.0;
    double ih = fmin(bb.w, cj.w) - fmax(bb.y, cj.y) + 1.0;
    iw = fmax(iw, 0.0); ih = fmax(ih, 0.0);
    double inter = iw * ih;
    double iou = inter / (ai + ca[jj] - inter);
    if (iou > 0.7) word |= (1ull << jj);
  }
  mask[(u32)i * NMS_WORDS + bj] = word;
}

// -------------------- serial NMS scan + top-300 select + output write (1 block)
__global__ __launch_bounds__(256)
void nms_finalize(const u64* __restrict__ mask, const double4* __restrict__ boxes,
                  const float* __restrict__ tscore, float* __restrict__ out)
{
  __shared__ u64 rem[NMS_WORDS];
  __shared__ u64 alv[NMS_WORDS];
  __shared__ int rows[68];
  __shared__ int nrows;
  __shared__ int pre[NMS_WORDS + 1];
  __shared__ int keep[POST_TOPN];
  const int tid = threadIdx.x;
  if (tid < NMS_WORDS) rem[tid] = 0ull;
  __syncthreads();

  for (int c = 0; c < NMS_WORDS; ++c) {
    if (tid < 64) {
      int row = c * 64 + tid;
      u64 m = (row < PRE_TOPN) ? mask[(u32)row * NMS_WORDS + c] : 0ull;
      u64 cur = rem[c];
      for (int b = 0; b < 64; ++b) {
        u64 mb = (u64)__shfl((long long)m, b, 64);
        if (!((cur >> b) & 1ull)) cur |= mb;
      }
      if (tid == 0) {
        rem[c] = cur;
        u64 valid = (c == NMS_WORDS - 1) ? ((1ull << 48) - 1ull) : ~0ull;
        alv[c] = (~cur) & valid;
      }
    }
    if (tid == 255) nrows = 0;
    __syncthreads();
    if (tid < 64 && ((alv[c] >> tid) & 1ull))
      rows[atomicAdd(&nrows, 1)] = c * 64 + tid;
    __syncthreads();
    const int nr = nrows;
    if (tid < 4 && nr > 0) rows[nr + tid] = rows[0];
    __syncthreads();
    if (nr > 0) {
      int w = c + 1 + (tid >> 1);
      if (w < NMS_WORDS) {
        const int sl = tid & 1;
        const int G = (nr + 3) >> 2;
        u64 acc = 0ull;
        for (int g = sl; g < G; g += 2) {
          int b = g << 2;
          int r0 = rows[b], r1 = rows[b + 1], r2 = rows[b + 2], r3 = rows[b + 3];
          acc |= mask[(u32)r0 * NMS_WORDS + w] | mask[(u32)r1 * NMS_WORDS + w]
               | mask[(u32)r2 * NMS_WORDS + w] | mask[(u32)r3 * NMS_WORDS + w];
        }
        if (acc) atomicOr((unsigned long long*)&rem[w], (unsigned long long)acc);
      }
    }
    __syncthreads();
  }

  if (tid == 0) {
    int s = 0;
    for (int c = 0; c < NMS_WORDS; ++c) { pre[c] = s; s += __popcll(alv[c]); }
    pre[NMS_WORDS] = s;
  }
  __syncthreads();
  const int total = pre[NMS_WORDS];
  if (tid < NMS_WORDS) {
    int p = pre[tid];
    u64 bits = alv[tid];
    while (bits && p < POST_TOPN) {
      int b = __ffsll(bits) - 1;
      bits &= bits - 1;
      keep[p] = tid * 64 + b;
      ++p;
    }
  }
  __syncthreads();
  if (total < POST_TOPN) {
    if (tid == 0) {
      int p = total;
      for (int c = 0; c < NMS_WORDS && p < POST_TOPN; ++c) {
        u64 valid = (c == NMS_WORDS - 1) ? ((1ull << 48) - 1ull) : ~0ull;
        u64 bits = rem[c] & valid;
        while (bits && p < POST_TOPN) {
          int b = __ffsll(bits) - 1;
          bits &= bits - 1;
          keep[p++] = c * 64 + b;
        }
      }
    }
    __syncthreads();
  }

  for (int t = tid; t < POST_TOPN; t += 256) {
    int r = keep[t];
    double4 b = boxes[r];
    out[t * 5 + 0] = 0.f;
    out[t * 5 + 1] = (float)b.x;
    out[t * 5 + 2] = (float)b.y;
    out[t * 5 + 3] = (float)b.z;
    out[t * 5 + 4] = (float)b.w;
    out[POST_TOPN * 5 + t] = tscore[r];
  }
}

// --------------------------------------------------------------------- launch
extern "C" void kernel_launch(void* const* d_in, const int* in_sizes, int n_in,
                              void* d_out, int out_size, void* d_ws, size_t ws_size,
                              hipStream_t stream)
{
  const float* feature = (const float*)d_in[0];
  const int*   im_info = (const int*)d_in[1];
  const float* w_conv  = (const float*)d_in[2];
  const float* b_conv  = (const float*)d_in[3];
  const float* w_sc    = (const float*)d_in[4];
  const float* b_sc    = (const float*)d_in[5];
  const float* w_bb    = (const float*)d_in[6];
  const float* b_bb    = (const float*)d_in[7];
  float* out = (float*)d_out;

  char* ws = (char*)d_ws;
  float*   rfeat  = (float*)(ws);                 // [0, 32M)
  // wd: [33,554,432 , 52,428,800) -- live only during conv3x3; everything
  // below overlaps it TEMPORALLY (written only after conv3x3 completes).
  double*  wd     = (double*)(ws + 33554432);     // 18,874,368 B
  float*   scores = (float*)(ws + 33554432);      //    589,824 B (post-conv)
  double4* props  = (double4*)(ws + 34144256);    //  4,718,592 B (post-conv)
  u64*     mask   = (u64*)(ws + 34144256);        // alias props (post-sort)
  u32*     hist   = (u32*)(ws + 38862848);        //    262,144 B (post-conv)
  u32*     scal   = (u32*)(ws + 39124992);        //        256 B (post-conv)
  u64*     cand   = (u64*)(ws + 39125248);        //    131,072 B
  float*   tscore = (float*)(ws + 39256320);      //     24,000 B
  double4* boxes  = (double4*)(ws + 39280384);    //    192,000 B

  const bool big = (ws_size >= 52428800ull);
  if (big) {
    wcvt<<<9216, 256, 0, stream>>>(w_conv, wd);
    conv3x3<<<1024, 512, 0, stream>>>(feature, wd, b_conv, rfeat);
  } else {
    conv3x3_fb<<<1024, 256, 0, stream>>>(feature, w_conv, b_conv, rfeat);
  }

  // memsets AFTER conv3x3: hist/scal bytes alias the wd region.
  hipMemsetAsync(hist, 0, 65536 * sizeof(u32), stream);
  hipMemsetAsync(scal, 0, 256, stream);

  conv1x1_decode<<<256, 256, 0, stream>>>(rfeat, w_sc, b_sc, w_bb, b_bb, im_info,
                                          scores, props, hist);
  scan_hist<<<1, 1024, 0, stream>>>(hist, scal);
  compact_cand<<<(NTOT + 255) / 256, 256, 0, stream>>>(scores, scal, cand);
  sort_topk<<<1, 1024, 0, stream>>>(cand, scal, props, tscore, boxes);
  nms_mask<<<dim3(NMS_WORDS, NMS_WORDS), 64, 0, stream>>>(boxes, mask);
  nms_finalize<<<1, 256, 0, stream>>>(mask, boxes, tscore, out);

  hipMemcpyAsync(out + POST_TOPN * 6, feature, (size_t)CC * HW * sizeof(float),
                 hipMemcpyDeviceToDevice, stream);
}